// Round 3
// baseline (450.628 us; speedup 1.0000x reference)
//
#include <hip/hip_runtime.h>
#include <hip/hip_bf16.h>
#include <stdint.h>

typedef __attribute__((ext_vector_type(8))) short bf16x8;
typedef __attribute__((ext_vector_type(4))) float f32x4;

__device__ __forceinline__ unsigned short f2b(float x) {
  __hip_bfloat16 h = __float2bfloat16(x);
  unsigned short u;
  __builtin_memcpy(&u, &h, 2);
  return u;
}

__device__ __forceinline__ void glds16(const void* g, void* l) {
  __builtin_amdgcn_global_load_lds((const __attribute__((address_space(1))) void*)g,
                                   (__attribute__((address_space(3))) void*)l,
                                   16, 0, 0);
}

__device__ __forceinline__ float wred_add(float v) {
#pragma unroll
  for (int o = 32; o >= 1; o >>= 1) v += __shfl_xor(v, o, 64);
  return v;
}

// ---------------------------------------------------------------------------
// Fused QKV projection GEMM. A = h [32768][256] bf16. z selects output:
//   z=0: q  = (h@wq + bq) * qscale   (qscale folds 1/sqrt(C) * log2e)
//   z=1: kk = h@wk + bk
//   z=2: vT = h@wv + bv, stored transposed per batch: [B][256][4096]
// 128x128 tile, BK=32, 4 waves (m97 structure).
// ---------------------------------------------------------------------------
__global__ __launch_bounds__(256) void gemm_qkv(
    const unsigned short* __restrict__ h, const unsigned short* __restrict__ wT,
    const float* __restrict__ bq, const float* __restrict__ bk, const float* __restrict__ bv,
    unsigned short* __restrict__ q, unsigned short* __restrict__ kk,
    unsigned short* __restrict__ vT, float qscale)
{
  __shared__ unsigned short As[128 * 32];
  __shared__ unsigned short Bs[128 * 32];
  const int t = threadIdx.x;
  const int lane = t & 63;
  const int wv_ = t >> 6;
  const int wr = wv_ >> 1, wc = wv_ & 1;
  const int z = blockIdx.z;
  const long long row0 = (long long)blockIdx.y * 128;
  const int col0 = blockIdx.x * 128;
  const unsigned short* Bt = wT + z * 65536;
  const float* bias = z == 0 ? bq : z == 1 ? bk : bv;
  const float scale = z == 0 ? qscale : 1.0f;

  const int sr = t >> 2;
  const int sc = (t & 3) * 8;
  const unsigned short* ga = h + (row0 + sr) * 256 + sc;
  const unsigned short* gb = Bt + (col0 + sr) * 256 + sc;
  char* lA = (char*)As + (t >> 6) * 1024;
  char* lB = (char*)Bs + (t >> 6) * 1024;

  const int l15 = lane & 15;
  const int l4 = lane >> 4;
  const unsigned short* pa = As + (wr * 64 + l15) * 32 + l4 * 8;
  const unsigned short* pb = Bs + (wc * 64 + l15) * 32 + l4 * 8;

  f32x4 acc[4][4] = {};

  for (int k0 = 0; k0 < 256; k0 += 32) {
    glds16(ga, lA);
    glds16(ga + 64 * 256, lA + 4096);
    glds16(gb, lB);
    glds16(gb + 64 * 256, lB + 4096);
    ga += 32;
    gb += 32;
    __syncthreads();
    bf16x8 a[4], b[4];
#pragma unroll
    for (int i = 0; i < 4; i++) a[i] = *(const bf16x8*)(pa + i * 512);
#pragma unroll
    for (int j = 0; j < 4; j++) b[j] = *(const bf16x8*)(pb + j * 512);
#pragma unroll
    for (int i = 0; i < 4; i++)
#pragma unroll
      for (int j = 0; j < 4; j++)
        acc[i][j] = __builtin_amdgcn_mfma_f32_16x16x32_bf16(a[i], b[j], acc[i][j], 0, 0, 0);
    __syncthreads();
  }

#pragma unroll
  for (int i = 0; i < 4; i++) {
#pragma unroll
    for (int j = 0; j < 4; j++) {
      const int col = col0 + wc * 64 + j * 16 + l15;
      const float bv_ = bias[col];
#pragma unroll
      for (int r = 0; r < 4; r++) {
        const long long row = row0 + wr * 64 + i * 16 + l4 * 4 + r;
        const float val = (acc[i][j][r] + bv_) * scale;
        if (z == 0) {
          q[row * 256 + col] = f2b(val);
        } else if (z == 1) {
          kk[row * 256 + col] = f2b(val);
        } else {
          const int bb = (int)(row >> 12), rr = (int)(row & 4095);
          vT[((long long)bb * 256 + col) * 4096 + rr] = f2b(val);
        }
      }
    }
  }
}

// ---------------------------------------------------------------------------
// Final projection + residual: out = x + oo@woT + bo   (f32 out)
// ---------------------------------------------------------------------------
__global__ __launch_bounds__(256) void gemm_out(
    const unsigned short* __restrict__ A, const unsigned short* __restrict__ Bt,
    float* __restrict__ C, const float* __restrict__ bias,
    const float* __restrict__ resid)
{
  __shared__ unsigned short As[128 * 32];
  __shared__ unsigned short Bs[128 * 32];
  const int t = threadIdx.x;
  const int lane = t & 63;
  const int wv_ = t >> 6;
  const int wr = wv_ >> 1, wc = wv_ & 1;
  const long long row0 = (long long)blockIdx.y * 128;
  const int col0 = blockIdx.x * 128;

  const int sr = t >> 2;
  const int sc = (t & 3) * 8;
  const unsigned short* ga = A + (row0 + sr) * 256 + sc;
  const unsigned short* gb = Bt + (col0 + sr) * 256 + sc;
  char* lA = (char*)As + (t >> 6) * 1024;
  char* lB = (char*)Bs + (t >> 6) * 1024;

  const int l15 = lane & 15;
  const int l4 = lane >> 4;
  const unsigned short* pa = As + (wr * 64 + l15) * 32 + l4 * 8;
  const unsigned short* pb = Bs + (wc * 64 + l15) * 32 + l4 * 8;

  f32x4 acc[4][4] = {};

  for (int k0 = 0; k0 < 256; k0 += 32) {
    glds16(ga, lA);
    glds16(ga + 64 * 256, lA + 4096);
    glds16(gb, lB);
    glds16(gb + 64 * 256, lB + 4096);
    ga += 32;
    gb += 32;
    __syncthreads();
    bf16x8 a[4], b[4];
#pragma unroll
    for (int i = 0; i < 4; i++) a[i] = *(const bf16x8*)(pa + i * 512);
#pragma unroll
    for (int j = 0; j < 4; j++) b[j] = *(const bf16x8*)(pb + j * 512);
#pragma unroll
    for (int i = 0; i < 4; i++)
#pragma unroll
      for (int j = 0; j < 4; j++)
        acc[i][j] = __builtin_amdgcn_mfma_f32_16x16x32_bf16(a[i], b[j], acc[i][j], 0, 0, 0);
    __syncthreads();
  }

#pragma unroll
  for (int i = 0; i < 4; i++) {
#pragma unroll
    for (int j = 0; j < 4; j++) {
      const int col = col0 + wc * 64 + j * 16 + l15;
      const float bv_ = bias[col];
#pragma unroll
      for (int r = 0; r < 4; r++) {
        const long long row = row0 + wr * 64 + i * 16 + l4 * 4 + r;
        const long long idx = row * 256 + col;
        C[idx] = resid[idx] + acc[i][j][r] + bv_;
      }
    }
  }
}

// ---------------------------------------------------------------------------
// LayerNorm over C=256, one row per block, fp32 in -> bf16 out
// ---------------------------------------------------------------------------
__global__ __launch_bounds__(256) void ln_bf16(const float* __restrict__ x,
                                               const float* __restrict__ gamma,
                                               const float* __restrict__ beta,
                                               unsigned short* __restrict__ h)
{
  const long long row = blockIdx.x;
  const float* xr = x + row * 256;
  const int t = threadIdx.x;
  const float v = xr[t];
  float s = wred_add(v);
  float s2 = wred_add(v * v);
  __shared__ float red[8];
  const int w = t >> 6, lane = t & 63;
  if (lane == 0) { red[w] = s; red[4 + w] = s2; }
  __syncthreads();
  s = red[0] + red[1] + red[2] + red[3];
  s2 = red[4] + red[5] + red[6] + red[7];
  const float mean = s * (1.f / 256.f);
  const float var = s2 * (1.f / 256.f) - mean * mean;
  const float rstd = rsqrtf(var + 1e-3f);
  h[row * 256 + t] = f2b((v - mean) * rstd * gamma[t] + beta[t]);
}

// ---------------------------------------------------------------------------
// Transpose + bf16-cast the four 256x256 weights
// ---------------------------------------------------------------------------
__global__ void wtrans(const float* __restrict__ wq, const float* __restrict__ wk,
                       const float* __restrict__ wv, const float* __restrict__ wo,
                       unsigned short* __restrict__ wT)
{
  const float* w = blockIdx.z == 0 ? wq : blockIdx.z == 1 ? wk : blockIdx.z == 2 ? wv : wo;
  unsigned short* o = wT + (long long)blockIdx.z * 65536;
  __shared__ float tile[16][17];
  const int tx = threadIdx.x, ty = threadIdx.y;
  const int bx = blockIdx.x * 16, by = blockIdx.y * 16;
  tile[ty][tx] = w[(by + ty) * 256 + bx + tx];
  __syncthreads();
  o[(bx + ty) * 256 + (by + tx)] = f2b(tile[tx][ty]);
}

// ---------------------------------------------------------------------------
// Fused flash attention.
// Flat grid of 512 blocks; batch = blockIdx.x & 7  -> all 64 blocks of a batch
// land on one XCD (round-robin dispatch), so that batch's K+V (4MB) stays
// L2-resident. 256 thr = 4 waves, each wave owns 16 q-rows (QBLK=64).
// KVBLK=32, K/V double-buffered. LDS = 68KB -> 2 blocks/CU (2 waves/SIMD).
//   K[2]: 2x16KB @0   V[2]: 2x16KB @32K   P: 4 waves x 1KB @64K
// K rows (512B) swizzled: granule ^= (row&7). V rows (64B): granule ^= (d>>1)&3.
// P [16q][32k] rows (64B): granule ^= ((row ^ (row>>2))&3)  (spreads over l4).
// Q (pre-scaled by log2e/sqrt(C)) in registers; softmax in exp2 domain.
// ---------------------------------------------------------------------------
#define FL_LDS (68 * 1024)

__global__ __launch_bounds__(256) void flash(
    const unsigned short* __restrict__ q,   // [B][4096][256] bf16 (scaled)
    const unsigned short* __restrict__ kk,  // [B][4096][256] bf16
    const unsigned short* __restrict__ vT,  // [B][256][4096] bf16
    unsigned short* __restrict__ oo)        // [B][4096][256] bf16
{
  extern __shared__ char lds[];
  const int t = threadIdx.x;
  const int w = t >> 6;
  const int lane = t & 63;
  const int l15 = lane & 15, l4 = lane >> 4;
  const int b = blockIdx.x & 7;
  const int qb = blockIdx.x >> 3;
  const long long qrow = (long long)b * 4096 + (long long)qb * 64 + w * 16;

  const unsigned short* kbase = kk + (long long)b * 4096 * 256;
  const unsigned short* vbase = vT + (long long)b * 256 * 4096;

  // staging sources (pre-swizzled so linear LDS dest yields swizzled layout)
  const int gs_k = (t & 31) ^ ((t >> 5) & 7);
  const unsigned short* Kst = kbase + (t >> 5) * 256 + gs_k * 8;
  const int gs_v = (t & 3) ^ ((t >> 3) & 3);
  const unsigned short* Vst = vbase + (long long)(t >> 2) * 4096 + gs_v * 8;
  char* const Praw = lds + 65536 + w * 1024;

  // Q fragments: rows qrow + l15, k = ks*32 + l4*8
  bf16x8 Qf[8];
  {
    const unsigned short* qp = q + (qrow + l15) * 256 + l4 * 8;
#pragma unroll
    for (int ks = 0; ks < 8; ks++) Qf[ks] = *(const bf16x8*)(qp + ks * 32);
  }

  f32x4 O[16] = {};
  float mrow[4], lrow[4];
#pragma unroll
  for (int r = 0; r < 4; r++) { mrow[r] = -1e30f; lrow[r] = 0.f; }

  auto stage = [&](int it, int c) {
    const unsigned short* ks_ = Kst + (long long)it * 32 * 256;
    const unsigned short* vs_ = Vst + it * 32;
    char* kd = lds + c * 16384 + w * 1024;
    char* vd = lds + 32768 + c * 16384 + w * 1024;
#pragma unroll
    for (int p = 0; p < 4; p++) {
      glds16(ks_ + p * 8 * 256, kd + p * 4096);
      glds16(vs_ + (long long)p * 64 * 4096, vd + p * 4096);
    }
  };

  stage(0, 0);

  for (int it = 0; it < 128; ++it) {
    const int cur = it & 1;
    __syncthreads();  // buf[cur] staged (vmcnt drained at barrier)
    if (it < 127) stage(it + 1, cur ^ 1);
    const char* Kb = lds + cur * 16384;
    const char* Vb = lds + 32768 + cur * 16384;

    // S = Q K^T : D[col = key = j*16+l15, row = q = l4*4+r]
    f32x4 S[2] = {};
    __builtin_amdgcn_s_setprio(1);
#pragma unroll
    for (int ks = 0; ks < 8; ks++) {
#pragma unroll
      for (int j = 0; j < 2; j++) {
        const int key = j * 16 + l15;
        bf16x8 Kf = *(const bf16x8*)(Kb + key * 512 +
                                     ((ks * 64 + l4 * 16) ^ ((key & 7) << 4)));
        S[j] = __builtin_amdgcn_mfma_f32_16x16x32_bf16(Qf[ks], Kf, S[j], 0, 0, 0);
      }
    }
    __builtin_amdgcn_s_setprio(0);

    // online softmax (all 16 lanes of an l4-group share q-row l4*4+r)
#pragma unroll
    for (int r = 0; r < 4; r++) {
      float mx = fmaxf(S[0][r], S[1][r]);
#pragma unroll
      for (int msk = 1; msk <= 8; msk <<= 1) mx = fmaxf(mx, __shfl_xor(mx, msk, 64));
      const float mn = fmaxf(mrow[r], mx);
      const float rs_ = exp2f(mrow[r] - mn);
      mrow[r] = mn;
      const float e0 = exp2f(S[0][r] - mn);
      const float e1 = exp2f(S[1][r] - mn);
      S[0][r] = e0;
      S[1][r] = e1;
      float sum = e0 + e1;
#pragma unroll
      for (int msk = 1; msk <= 8; msk <<= 1) sum += __shfl_xor(sum, msk, 64);
      lrow[r] = lrow[r] * rs_ + sum;
#pragma unroll
      for (int jd = 0; jd < 16; jd++) O[jd][r] *= rs_;
    }

    // P -> LDS (bf16, swizzled)
#pragma unroll
    for (int j = 0; j < 2; j++)
#pragma unroll
      for (int r = 0; r < 4; r++) {
        const int row = l4 * 4 + r;
        const int s = (row ^ (row >> 2)) & 3;
        *(unsigned short*)(Praw + row * 64 +
                           (((j * 16 + l15) * 2) ^ (s << 4))) = f2b(S[j][r]);
      }

    // PV: O += P V^T
    bf16x8 Pf;
    {
      const int s = (l15 ^ (l15 >> 2)) & 3;
      Pf = *(const bf16x8*)(Praw + l15 * 64 + ((l4 * 16) ^ (s << 4)));
    }
    __builtin_amdgcn_s_setprio(1);
#pragma unroll
    for (int jd = 0; jd < 16; jd++) {
      const int d = jd * 16 + l15;
      bf16x8 Vf = *(const bf16x8*)(Vb + d * 64 + ((l4 ^ ((d >> 1) & 3)) * 16));
      O[jd] = __builtin_amdgcn_mfma_f32_16x16x32_bf16(Pf, Vf, O[jd], 0, 0, 0);
    }
    __builtin_amdgcn_s_setprio(0);
  }

  // epilogue
  float inv[4];
#pragma unroll
  for (int r = 0; r < 4; r++) inv[r] = 1.f / lrow[r];
#pragma unroll
  for (int jd = 0; jd < 16; jd++)
#pragma unroll
    for (int r = 0; r < 4; r++) {
      const long long row = qrow + l4 * 4 + r;
      oo[row * 256 + jd * 16 + l15] = f2b(O[jd][r] * inv[r]);
    }
}

// ---------------------------------------------------------------------------
extern "C" void kernel_launch(void* const* d_in, const int* in_sizes, int n_in,
                              void* d_out, int out_size, void* d_ws, size_t ws_size,
                              hipStream_t stream)
{
  const float* x = (const float*)d_in[0];
  const float* gamma = (const float*)d_in[1];
  const float* beta = (const float*)d_in[2];
  const float* wq = (const float*)d_in[3];
  const float* bq = (const float*)d_in[4];
  const float* wk = (const float*)d_in[5];
  const float* bk = (const float*)d_in[6];
  const float* wv = (const float*)d_in[7];
  const float* bv = (const float*)d_in[8];
  const float* wo = (const float*)d_in[9];
  const float* bo = (const float*)d_in[10];

  const int Cc = 256;
  const long long MR = 32768;  // 8 * 4096

  char* base = (char*)d_ws;
  size_t off = 0;
  auto take = [&](size_t bytes) -> char* {
    char* p = base + off;
    off = (off + bytes + 255) & ~(size_t)255;
    return p;
  };
  unsigned short* h  = (unsigned short*)take((size_t)MR * Cc * 2);
  unsigned short* q  = (unsigned short*)take((size_t)MR * Cc * 2);  // scaled
  unsigned short* kk = (unsigned short*)take((size_t)MR * Cc * 2);
  unsigned short* vT = (unsigned short*)take((size_t)MR * Cc * 2);  // [B][C][4096]
  unsigned short* oo = (unsigned short*)take((size_t)MR * Cc * 2);
  unsigned short* wT = (unsigned short*)take(4ull * Cc * Cc * 2);

  wtrans<<<dim3(16, 16, 4), dim3(16, 16), 0, stream>>>(wq, wk, wv, wo, wT);
  ln_bf16<<<dim3((unsigned)MR), dim3(256), 0, stream>>>(x, gamma, beta, h);

  const float qscale = 0.0625f * 1.44269504f;  // 1/sqrt(256) * log2(e)
  gemm_qkv<<<dim3(2, 256, 3), 256, 0, stream>>>(h, wT, bq, bk, bv, q, kk, vT, qscale);

  flash<<<dim3(512), dim3(256), FL_LDS, stream>>>(q, kk, vT, oo);

  gemm_out<<<dim3(2, 256, 1), 256, 0, stream>>>(oo, wT + 3 * 65536, (float*)d_out, bo, x);
}

// Round 6
// 323.321 us; speedup vs baseline: 1.3937x; 1.3937x over previous
//
#include <hip/hip_runtime.h>
#include <hip/hip_bf16.h>
#include <stdint.h>

typedef __attribute__((ext_vector_type(8))) short bf16x8;
typedef __attribute__((ext_vector_type(4))) short bf16x4;
typedef __attribute__((ext_vector_type(4))) float f32x4;

__device__ __forceinline__ unsigned short f2b(float x) {
  __hip_bfloat16 h = __float2bfloat16(x);
  unsigned short u;
  __builtin_memcpy(&u, &h, 2);
  return u;
}

__device__ __forceinline__ void glds16(const void* g, void* l) {
  __builtin_amdgcn_global_load_lds((const __attribute__((address_space(1))) void*)g,
                                   (__attribute__((address_space(3))) void*)l,
                                   16, 0, 0);
}

__device__ __forceinline__ float wred_add(float v) {
#pragma unroll
  for (int o = 32; o >= 1; o >>= 1) v += __shfl_xor(v, o, 64);
  return v;
}

// ---------------------------------------------------------------------------
// Fused QKV projection GEMM (m97 structure, 128x128 tile, BK=32, 4 waves).
//   z=0: q  = (h@wq + bq) * qscale   (qscale folds 1/sqrt(C) * log2e)
//   z=1: kk = h@wk + bk
//   z=2: vT = h@wv + bv, stored transposed per batch [B][256][4096], with the
//        position index k-permuted within each 32-chunk:
//        pos(k) = ((k>>2)&3)*8 + ((k>>4)&1)*4 + (k&3)
//        so flash's PV A-fragment is one contiguous 16B LDS read.
// ---------------------------------------------------------------------------
__global__ __launch_bounds__(256) void gemm_qkv(
    const unsigned short* __restrict__ h, const unsigned short* __restrict__ wT,
    const float* __restrict__ bq, const float* __restrict__ bk, const float* __restrict__ bv,
    unsigned short* __restrict__ q, unsigned short* __restrict__ kk,
    unsigned short* __restrict__ vT, float qscale)
{
  __shared__ unsigned short As[128 * 32];
  __shared__ unsigned short Bs[128 * 32];
  const int t = threadIdx.x;
  const int lane = t & 63;
  const int wv_ = t >> 6;
  const int wr = wv_ >> 1, wc = wv_ & 1;
  const int z = blockIdx.z;
  const long long row0 = (long long)blockIdx.y * 128;
  const int col0 = blockIdx.x * 128;
  const unsigned short* Bt = wT + z * 65536;
  const float* bias = z == 0 ? bq : z == 1 ? bk : bv;
  const float scale = z == 0 ? qscale : 1.0f;

  const int sr = t >> 2;
  const int sc = (t & 3) * 8;
  const unsigned short* ga = h + (row0 + sr) * 256 + sc;
  const unsigned short* gb = Bt + (col0 + sr) * 256 + sc;
  char* lA = (char*)As + (t >> 6) * 1024;
  char* lB = (char*)Bs + (t >> 6) * 1024;

  const int l15 = lane & 15;
  const int l4 = lane >> 4;
  const unsigned short* pa = As + (wr * 64 + l15) * 32 + l4 * 8;
  const unsigned short* pb = Bs + (wc * 64 + l15) * 32 + l4 * 8;

  f32x4 acc[4][4] = {};

  for (int k0 = 0; k0 < 256; k0 += 32) {
    glds16(ga, lA);
    glds16(ga + 64 * 256, lA + 4096);
    glds16(gb, lB);
    glds16(gb + 64 * 256, lB + 4096);
    ga += 32;
    gb += 32;
    __syncthreads();
    bf16x8 a[4], b[4];
#pragma unroll
    for (int i = 0; i < 4; i++) a[i] = *(const bf16x8*)(pa + i * 512);
#pragma unroll
    for (int j = 0; j < 4; j++) b[j] = *(const bf16x8*)(pb + j * 512);
#pragma unroll
    for (int i = 0; i < 4; i++)
#pragma unroll
      for (int j = 0; j < 4; j++)
        acc[i][j] = __builtin_amdgcn_mfma_f32_16x16x32_bf16(a[i], b[j], acc[i][j], 0, 0, 0);
    __syncthreads();
  }

#pragma unroll
  for (int i = 0; i < 4; i++) {
#pragma unroll
    for (int j = 0; j < 4; j++) {
      const int col = col0 + wc * 64 + j * 16 + l15;
      const float bv_ = bias[col];
#pragma unroll
      for (int r = 0; r < 4; r++) {
        const long long row = row0 + wr * 64 + i * 16 + l4 * 4 + r;
        const float val = (acc[i][j][r] + bv_) * scale;
        if (z == 0) {
          q[row * 256 + col] = f2b(val);
        } else if (z == 1) {
          kk[row * 256 + col] = f2b(val);
        } else {
          const int bb = (int)(row >> 12), rr = (int)(row & 4095);
          const int kl = rr & 31;
          const int rrp = (rr & ~31) | ((((kl >> 2) & 3) << 3) | (((kl >> 4) & 1) << 2) | (kl & 3));
          vT[((long long)bb * 256 + col) * 4096 + rrp] = f2b(val);
        }
      }
    }
  }
}

// ---------------------------------------------------------------------------
// Final projection + residual: out = x + oo@woT + bo   (f32 out)
// ---------------------------------------------------------------------------
__global__ __launch_bounds__(256) void gemm_out(
    const unsigned short* __restrict__ A, const unsigned short* __restrict__ Bt,
    float* __restrict__ C, const float* __restrict__ bias,
    const float* __restrict__ resid)
{
  __shared__ unsigned short As[128 * 32];
  __shared__ unsigned short Bs[128 * 32];
  const int t = threadIdx.x;
  const int lane = t & 63;
  const int wv_ = t >> 6;
  const int wr = wv_ >> 1, wc = wv_ & 1;
  const long long row0 = (long long)blockIdx.y * 128;
  const int col0 = blockIdx.x * 128;

  const int sr = t >> 2;
  const int sc = (t & 3) * 8;
  const unsigned short* ga = A + (row0 + sr) * 256 + sc;
  const unsigned short* gb = Bt + (col0 + sr) * 256 + sc;
  char* lA = (char*)As + (t >> 6) * 1024;
  char* lB = (char*)Bs + (t >> 6) * 1024;

  const int l15 = lane & 15;
  const int l4 = lane >> 4;
  const unsigned short* pa = As + (wr * 64 + l15) * 32 + l4 * 8;
  const unsigned short* pb = Bs + (wc * 64 + l15) * 32 + l4 * 8;

  f32x4 acc[4][4] = {};

  for (int k0 = 0; k0 < 256; k0 += 32) {
    glds16(ga, lA);
    glds16(ga + 64 * 256, lA + 4096);
    glds16(gb, lB);
    glds16(gb + 64 * 256, lB + 4096);
    ga += 32;
    gb += 32;
    __syncthreads();
    bf16x8 a[4], b[4];
#pragma unroll
    for (int i = 0; i < 4; i++) a[i] = *(const bf16x8*)(pa + i * 512);
#pragma unroll
    for (int j = 0; j < 4; j++) b[j] = *(const bf16x8*)(pb + j * 512);
#pragma unroll
    for (int i = 0; i < 4; i++)
#pragma unroll
      for (int j = 0; j < 4; j++)
        acc[i][j] = __builtin_amdgcn_mfma_f32_16x16x32_bf16(a[i], b[j], acc[i][j], 0, 0, 0);
    __syncthreads();
  }

#pragma unroll
  for (int i = 0; i < 4; i++) {
#pragma unroll
    for (int j = 0; j < 4; j++) {
      const int col = col0 + wc * 64 + j * 16 + l15;
      const float bv_ = bias[col];
#pragma unroll
      for (int r = 0; r < 4; r++) {
        const long long row = row0 + wr * 64 + i * 16 + l4 * 4 + r;
        const long long idx = row * 256 + col;
        C[idx] = resid[idx] + acc[i][j][r] + bv_;
      }
    }
  }
}

// ---------------------------------------------------------------------------
// LayerNorm over C=256, one row per block, fp32 in -> bf16 out
// ---------------------------------------------------------------------------
__global__ __launch_bounds__(256) void ln_bf16(const float* __restrict__ x,
                                               const float* __restrict__ gamma,
                                               const float* __restrict__ beta,
                                               unsigned short* __restrict__ h)
{
  const long long row = blockIdx.x;
  const float* xr = x + row * 256;
  const int t = threadIdx.x;
  const float v = xr[t];
  float s = wred_add(v);
  float s2 = wred_add(v * v);
  __shared__ float red[8];
  const int w = t >> 6, lane = t & 63;
  if (lane == 0) { red[w] = s; red[4 + w] = s2; }
  __syncthreads();
  s = red[0] + red[1] + red[2] + red[3];
  s2 = red[4] + red[5] + red[6] + red[7];
  const float mean = s * (1.f / 256.f);
  const float var = s2 * (1.f / 256.f) - mean * mean;
  const float rstd = rsqrtf(var + 1e-3f);
  h[row * 256 + t] = f2b((v - mean) * rstd * gamma[t] + beta[t]);
}

// ---------------------------------------------------------------------------
// Transpose + bf16-cast the four 256x256 weights
// ---------------------------------------------------------------------------
__global__ void wtrans(const float* __restrict__ wq, const float* __restrict__ wk,
                       const float* __restrict__ wv, const float* __restrict__ wo,
                       unsigned short* __restrict__ wT)
{
  const float* w = blockIdx.z == 0 ? wq : blockIdx.z == 1 ? wk : blockIdx.z == 2 ? wv : wo;
  unsigned short* o = wT + (long long)blockIdx.z * 65536;
  __shared__ float tile[16][17];
  const int tx = threadIdx.x, ty = threadIdx.y;
  const int bx = blockIdx.x * 16, by = blockIdx.y * 16;
  tile[ty][tx] = w[(by + ty) * 256 + bx + tx];
  __syncthreads();
  o[(bx + ty) * 256 + (by + tx)] = f2b(tile[tx][ty]);
}

// ---------------------------------------------------------------------------
// Fused flash attention, swapped-operand structure (all 16x16x32 MFMA).
// grid 256 flat; batch = blockIdx.x & 7 (XCD-pinned: batch's K/V L2-resident).
// 256 thr = 4 waves; wave owns 32 q-rows (2 q-groups of 16). KVBLK=32.
// LDS 64KB: K dbuf 2x16KB @0, V dbuf 2x16KB @32K. No P in LDS.
//
// QK^T (swapped): S^T = mfma(A=K_frag, B=Q_frag):
//   lane owns q-row = qg*16 + l15 (col); keys j*16 + hi*4 + r (row).
//   -> softmax in-lane over 8 vals + shfl_xor(16,32). m,l,rs are scalars.
// PV (swapped, K=32): O^T = mfma(A=Vf8, B=Pf8) with slot labeling
//   lambda(hi,idx) = (idx>>2)*16 + hi*4 + (idx&3) on BOTH operands:
//   Pf8[idx] = e[idx>>2][idx&3] (from S^T's verified C-layout);
//   Vf8 = ONE 16B LDS read (vT global layout is pre-permuted so positions
//   hi*8..hi*8+7 hold exactly k = lambda(hi, 0..7)).
//   Dot-product pairing is invariant to the HW k-map (A/B maps identical).
// K LDS rows 512B swizzled ^((key&7)<<4); V rows 64B swizzled ^((d&3)<<4);
// both achieved by pre-swizzling the per-lane GLOBAL staging source.
// Epilogue: O^T -> oo[q][d] via per-wave 16KB LDS slab (reuses K/V space);
// each lane writes its FULL 64-element d-chunk (half = 0..7).
// ---------------------------------------------------------------------------
#define FL_LDS (64 * 1024)

__global__ __launch_bounds__(256, 2) void flash(
    const unsigned short* __restrict__ q,   // [B][4096][256] bf16 (scaled by log2e/16)
    const unsigned short* __restrict__ kk,  // [B][4096][256] bf16
    const unsigned short* __restrict__ vT,  // [B][256][4096] bf16, k-permuted per 32
    unsigned short* __restrict__ oo)        // [B][4096][256] bf16
{
  extern __shared__ char lds[];
  const int t = threadIdx.x;
  const int w = t >> 6;
  const int lane = t & 63;
  const int l15 = lane & 15, hi = lane >> 4;
  const int b = blockIdx.x & 7;
  const int qb = blockIdx.x >> 3;
  const long long qrow = (long long)b * 4096 + (long long)qb * 128 + w * 32;

  const unsigned short* kbase = kk + (long long)b * 4096 * 256;
  const unsigned short* vbase = vT + (long long)b * 256 * 4096;

  // staging sources, pre-swizzled (16B granules):
  //  K tile [32 key][256 c]: instr p covers keys p*8+(t>>5); src granule (t&31)^((t>>5)&7)
  //  V tile [256 d][32 k]:   instr p covers d = p*64+(t>>2); src granule (t&3)^((t>>2)&3)
  const int gs_k = (t & 31) ^ ((t >> 5) & 7);
  const unsigned short* Kst = kbase + (t >> 5) * 256 + gs_k * 8;
  const int gs_v = (t & 3) ^ ((t >> 2) & 3);
  const unsigned short* Vst = vbase + (long long)(t >> 2) * 4096 + gs_v * 8;

  // Q fragments (B-operand): Qf[qg][ks]: q-row = qrow + qg*16 + l15, k = ks*32 + hi*8
  bf16x8 Qf[2][8];
  {
#pragma unroll
    for (int qg = 0; qg < 2; qg++) {
      const unsigned short* qp = q + (qrow + qg * 16 + l15) * 256 + hi * 8;
#pragma unroll
      for (int ks = 0; ks < 8; ks++) Qf[qg][ks] = *(const bf16x8*)(qp + ks * 32);
    }
  }

  f32x4 O[2][16] = {};
  float mrow[2] = {-1e30f, -1e30f};
  float lrow[2] = {0.f, 0.f};

  auto stage = [&](int it, int c) {
    const unsigned short* ks_ = Kst + (long long)it * 32 * 256;
    const unsigned short* vs_ = Vst + it * 32;
    char* kd = lds + c * 16384 + w * 1024;
    char* vd = lds + 32768 + c * 16384 + w * 1024;
#pragma unroll
    for (int p = 0; p < 4; p++) {
      glds16(ks_ + p * 8 * 256, kd + p * 4096);
      glds16(vs_ + (long long)p * 64 * 4096, vd + p * 4096);
    }
  };

  stage(0, 0);

  for (int it = 0; it < 128; ++it) {
    const int cur = it & 1;
    __syncthreads();  // buf[cur] staged (vmcnt drained at barrier)
    if (it < 127) stage(it + 1, cur ^ 1);
    const char* Kb = lds + cur * 16384;
    const char* Vb = lds + 32768 + cur * 16384;

    // S^T = K Q^T : per (j, qg): 8 k-steps of 16x16x32
    f32x4 S[2][2] = {};
    __builtin_amdgcn_s_setprio(1);
#pragma unroll
    for (int ks = 0; ks < 8; ks++) {
#pragma unroll
      for (int j = 0; j < 2; j++) {
        bf16x8 Kf = *(const bf16x8*)(Kb + (j * 16 + l15) * 512 +
                                     ((ks * 64 + hi * 16) ^ ((l15 & 7) << 4)));
        S[0][j] = __builtin_amdgcn_mfma_f32_16x16x32_bf16(Kf, Qf[0][ks], S[0][j], 0, 0, 0);
        S[1][j] = __builtin_amdgcn_mfma_f32_16x16x32_bf16(Kf, Qf[1][ks], S[1][j], 0, 0, 0);
      }
    }
    __builtin_amdgcn_s_setprio(0);

    // online softmax, in-lane (lane owns one q-row per qg), + P pack (bf16x8)
    bf16x8 Pf8[2];
#pragma unroll
    for (int qg = 0; qg < 2; qg++) {
      float mx = fmaxf(fmaxf(fmaxf(S[qg][0][0], S[qg][0][1]), fmaxf(S[qg][0][2], S[qg][0][3])),
                       fmaxf(fmaxf(S[qg][1][0], S[qg][1][1]), fmaxf(S[qg][1][2], S[qg][1][3])));
      mx = fmaxf(mx, __shfl_xor(mx, 16, 64));
      mx = fmaxf(mx, __shfl_xor(mx, 32, 64));
      const float mn = fmaxf(mrow[qg], mx);
      const float rs_ = exp2f(mrow[qg] - mn);
      mrow[qg] = mn;
      float sum = 0.f;
      float e[2][4];
#pragma unroll
      for (int j = 0; j < 2; j++)
#pragma unroll
        for (int r = 0; r < 4; r++) {
          e[j][r] = exp2f(S[qg][j][r] - mn);
          sum += e[j][r];
        }
      sum += __shfl_xor(sum, 16, 64);
      sum += __shfl_xor(sum, 32, 64);
      lrow[qg] = lrow[qg] * rs_ + sum;
      bf16x8 p;
#pragma unroll
      for (int j = 0; j < 2; j++)
#pragma unroll
        for (int r = 0; r < 4; r++) p[j * 4 + r] = (short)f2b(e[j][r]);
      Pf8[qg] = p;
#pragma unroll
      for (int dg = 0; dg < 16; dg++) O[qg][dg] *= rs_;
    }

    // PV: O^T += V' P'  (one 16x16x32 per (qg,dg); V-frag shared across qg)
    __builtin_amdgcn_s_setprio(1);
#pragma unroll
    for (int dg = 0; dg < 16; dg++) {
      bf16x8 Vf8 = *(const bf16x8*)(Vb + (dg * 16 + l15) * 64 +
                                    ((hi * 16) ^ ((l15 & 3) << 4)));
      O[0][dg] = __builtin_amdgcn_mfma_f32_16x16x32_bf16(Vf8, Pf8[0], O[0][dg], 0, 0, 0);
      O[1][dg] = __builtin_amdgcn_mfma_f32_16x16x32_bf16(Vf8, Pf8[1], O[1][dg], 0, 0, 0);
    }
    __builtin_amdgcn_s_setprio(0);
  }

  // epilogue: O^T/l -> transpose via per-wave LDS slab -> oo[q][d]
  __syncthreads();  // everyone done with K/V buffers
  char* const slab = lds + w * 16384;
#pragma unroll
  for (int qg = 0; qg < 2; qg++) {
    const float inv = 1.f / lrow[qg];
#pragma unroll
    for (int dg = 0; dg < 16; dg++) {
      f32x4 v = O[qg][dg] * inv;
      *(f32x4*)(slab + l15 * 1024 + ((dg * 64 + hi * 16) ^ ((l15 & 7) << 4))) = v;
    }
    // read rows: lane handles q-row = lane>>2, d-chunk = (lane&3)*64 (FULL 64)
    const int qq = lane >> 2;
    const int dc = lane & 3;
    const long long orow = (qrow + qg * 16 + qq) * 256 + dc * 64;
#pragma unroll
    for (int half = 0; half < 8; half++) {
      bf16x8 pack;
#pragma unroll
      for (int di = 0; di < 2; di++) {
        f32x4 v = *(const f32x4*)(slab + qq * 1024 +
                                  ((dc * 256 + half * 32 + di * 16) ^ ((qq & 7) << 4)));
#pragma unroll
        for (int e2 = 0; e2 < 4; e2++) pack[di * 4 + e2] = (short)f2b(v[e2]);
      }
      *(bf16x8*)(oo + orow + half * 8) = pack;
    }
    __syncthreads();  // slab reuse between qg passes (cheap, 2x per kernel)
  }
}

// ---------------------------------------------------------------------------
extern "C" void kernel_launch(void* const* d_in, const int* in_sizes, int n_in,
                              void* d_out, int out_size, void* d_ws, size_t ws_size,
                              hipStream_t stream)
{
  const float* x = (const float*)d_in[0];
  const float* gamma = (const float*)d_in[1];
  const float* beta = (const float*)d_in[2];
  const float* wq = (const float*)d_in[3];
  const float* bq = (const float*)d_in[4];
  const float* wk = (const float*)d_in[5];
  const float* bk = (const float*)d_in[6];
  const float* wv = (const float*)d_in[7];
  const float* bv = (const float*)d_in[8];
  const float* wo = (const float*)d_in[9];
  const float* bo = (const float*)d_in[10];

  const int Cc = 256;
  const long long MR = 32768;  // 8 * 4096

  char* base = (char*)d_ws;
  size_t off = 0;
  auto take = [&](size_t bytes) -> char* {
    char* p = base + off;
    off = (off + bytes + 255) & ~(size_t)255;
    return p;
  };
  unsigned short* h  = (unsigned short*)take((size_t)MR * Cc * 2);
  unsigned short* q  = (unsigned short*)take((size_t)MR * Cc * 2);  // scaled
  unsigned short* kk = (unsigned short*)take((size_t)MR * Cc * 2);
  unsigned short* vT = (unsigned short*)take((size_t)MR * Cc * 2);  // [B][C][4096] k-perm
  unsigned short* oo = (unsigned short*)take((size_t)MR * Cc * 2);
  unsigned short* wT = (unsigned short*)take(4ull * Cc * Cc * 2);

  wtrans<<<dim3(16, 16, 4), dim3(16, 16), 0, stream>>>(wq, wk, wv, wo, wT);
  ln_bf16<<<dim3((unsigned)MR), dim3(256), 0, stream>>>(x, gamma, beta, h);

  const float qscale = 0.0625f * 1.44269504f;  // 1/sqrt(256) * log2(e)
  gemm_qkv<<<dim3(2, 256, 3), 256, 0, stream>>>(h, wT, bq, bk, bv, q, kk, vT, qscale);

  flash<<<dim3(256), dim3(256), FL_LDS, stream>>>(q, kk, vT, oo);

  gemm_out<<<dim3(2, 256, 1), 256, 0, stream>>>(oo, wT + 3 * 65536, (float*)d_out, bo, x);
}